// Round 3
// baseline (1907.028 us; speedup 1.0000x reference)
//
#include <hip/hip_runtime.h>
#include <math.h>

#define BB 2048
#define SS 512
#define EE 384
#define FF 28
#define HH 32

// One block (256 thr = 4 waves) per batch element.
// Wave w handles rows s = w+1, w+5, ... (s in [1,512]); wave 0 additionally
// handles the s=0 "normed trainable" row. Online softmax per wave with the
// 384-dim embedding row as the value (r accumulator, 6 floats/lane), then a
// 4-way merge in LDS. Masked rows (~50%) are skipped entirely (attn weight
// is exactly 0) -- halves HBM traffic.
__global__ __launch_bounds__(256) void san_fused(
    const float* __restrict__ emb,       // [B,S,E]
    const int*   __restrict__ masks,     // [B,S]
    const float* __restrict__ feats,     // [B,F]
    const float* __restrict__ W_map,     // [F,H]
    const float* __restrict__ b_map,     // [H]
    const float* __restrict__ trainable, // [E]
    const float* __restrict__ W_k,       // [E,H]
    const float* __restrict__ b_k,       // [H]
    const float* __restrict__ W_v,       // [E,H]
    const float* __restrict__ b_v,       // [H]
    const float* __restrict__ W_c,       // [2H]
    const float* __restrict__ b_c,       // [1]
    float* __restrict__ logits,          // [B]
    float* __restrict__ attn)            // [B,S+1]
{
  __shared__ float q_s[HH];
  __shared__ float kq_s[EE];
  __shared__ float kb_s;
  __shared__ int   mask_s[SS];
  __shared__ float scores_s[SS + 1];
  __shared__ float wm[4], wl[4];
  __shared__ float wr[4][EE];
  __shared__ float rfin[EE];
  __shared__ float partial[8][HH];
  __shared__ float doc_s[HH];

  const int b    = blockIdx.x;
  const int tid  = threadIdx.x;
  const int lane = tid & 63;
  const int w    = tid >> 6;

  // ---- prologue: mask row -> LDS (coalesced) ----
  for (int i = tid; i < SS; i += 256) mask_s[i] = masks[(size_t)b * SS + i];

  // ---- q = features_b @ W_map + b_map  (32 threads, 28 MACs each) ----
  if (tid < HH) {
    float acc = b_map[tid];
    #pragma unroll
    for (int f = 0; f < FF; ++f)
      acc += feats[(size_t)b * FF + f] * W_map[f * HH + tid];
    q_s[tid] = acc;
  }
  __syncthreads();

  // ---- kq[e] = scale * sum_h W_k[e,h] q[h];  kb = scale * b_k . q ----
  const float scale = 0.17677669529663687f;  // 1/sqrt(32)
  for (int e = tid; e < EE; e += 256) {
    const float4* wrow = (const float4*)(W_k + (size_t)e * HH);
    float acc = 0.f;
    #pragma unroll
    for (int j = 0; j < HH / 4; ++j) {
      float4 v = wrow[j];
      acc += v.x * q_s[4*j] + v.y * q_s[4*j+1] + v.z * q_s[4*j+2] + v.w * q_s[4*j+3];
    }
    kq_s[e] = acc * scale;
  }
  if (tid == 0) {
    float acc = 0.f;
    #pragma unroll
    for (int h = 0; h < HH; ++h) acc += b_k[h] * q_s[h];
    kb_s = acc * scale;
  }
  __syncthreads();

  // per-lane kq registers matching the float2 load pattern:
  // lane owns elements {2L, 2L+1, 2L+128, 2L+129, 2L+256, 2L+257}
  const int e0 = 2 * lane;
  const float kq0 = kq_s[e0],       kq1 = kq_s[e0 + 1];
  const float kq2 = kq_s[e0 + 128], kq3 = kq_s[e0 + 129];
  const float kq4 = kq_s[e0 + 256], kq5 = kq_s[e0 + 257];
  const float kb  = kb_s;

  float m = -INFINITY, l = 0.f;
  float r0 = 0.f, r1 = 0.f, r2 = 0.f, r3 = 0.f, r4 = 0.f, r5 = 0.f;

  // ---- wave 0: s=0 row = trainable / ||trainable|| ----
  if (w == 0) {
    const float2* tp = (const float2*)trainable;
    const float2 t0 = tp[lane], t1 = tp[lane + 64], t2 = tp[lane + 128];
    float n2 = t0.x*t0.x + t0.y*t0.y + t1.x*t1.x + t1.y*t1.y + t2.x*t2.x + t2.y*t2.y;
    #pragma unroll
    for (int off = 32; off; off >>= 1) n2 += __shfl_xor(n2, off);
    const float inv_n = 1.0f / sqrtf(n2);   // full precision: feeds every score via row 0
    const float x0 = t0.x*inv_n, x1 = t0.y*inv_n, x2 = t1.x*inv_n;
    const float x3 = t1.y*inv_n, x4 = t2.x*inv_n, x5 = t2.y*inv_n;
    float dot = x0*kq0 + x1*kq1 + x2*kq2 + x3*kq3 + x4*kq4 + x5*kq5;
    #pragma unroll
    for (int off = 32; off; off >>= 1) dot += __shfl_xor(dot, off);
    const float sc = dot + kb;
    if (lane == 0) scores_s[0] = sc;
    m = sc; l = 1.f;
    r0 = x0; r1 = x1; r2 = x2; r3 = x3; r4 = x4; r5 = x5;
  }

  // ---- main loop: online softmax over this wave's rows ----
  const float* rowbase = emb + (size_t)b * SS * EE;
  for (int s = w + 1; s <= SS; s += 4) {
    if (mask_s[s - 1] != 0) {                 // wave-uniform branch
      if (lane == 0) scores_s[s] = -INFINITY; // exp -> exact 0 in epilogue
      continue;
    }
    const float2* rp = (const float2*)(rowbase + (size_t)(s - 1) * EE);
    const float2 a0 = rp[lane], a1 = rp[lane + 64], a2 = rp[lane + 128];
    float dot = a0.x*kq0 + a0.y*kq1 + a1.x*kq2 + a1.y*kq3 + a2.x*kq4 + a2.y*kq5;
    #pragma unroll
    for (int off = 32; off; off >>= 1) dot += __shfl_xor(dot, off);
    const float sc = dot + kb;
    if (lane == 0) scores_s[s] = sc;
    const float mn = fmaxf(m, sc);
    const float cc = __expf(m - mn);   // m=-inf first time -> 0, safe
    const float p  = __expf(sc - mn);
    l = l * cc + p;
    r0 = r0*cc + p*a0.x;  r1 = r1*cc + p*a0.y;
    r2 = r2*cc + p*a1.x;  r3 = r3*cc + p*a1.y;
    r4 = r4*cc + p*a2.x;  r5 = r5*cc + p*a2.y;
    m = mn;
  }

  // ---- merge 4 waves ----
  if (lane == 0) { wm[w] = m; wl[w] = l; }
  wr[w][e0]       = r0;  wr[w][e0 + 1]   = r1;
  wr[w][e0 + 128] = r2;  wr[w][e0 + 129] = r3;
  wr[w][e0 + 256] = r4;  wr[w][e0 + 257] = r5;
  __syncthreads();

  const float gm = fmaxf(fmaxf(wm[0], wm[1]), fmaxf(wm[2], wm[3]));
  const float c0 = __expf(wm[0] - gm), c1 = __expf(wm[1] - gm);
  const float c2 = __expf(wm[2] - gm), c3 = __expf(wm[3] - gm);
  const float gl = wl[0]*c0 + wl[1]*c1 + wl[2]*c2 + wl[3]*c3;
  const float inv_l = 1.f / gl;

  for (int e = tid; e < EE; e += 256)
    rfin[e] = wr[0][e]*c0 + wr[1][e]*c1 + wr[2][e]*c2 + wr[3][e]*c3;

  // ---- attn weights out (masked rows: scores=-inf -> exactly 0) ----
  float* arow = attn + (size_t)b * (SS + 1);
  for (int s = tid; s < SS + 1; s += 256)
    arow[s] = __expf(scores_s[s] - gm) * inv_l;
  __syncthreads();

  // ---- doc_repr = (rfin/l) @ W_v + b_v ; 8 chunks x 48 e x 32 h ----
  {
    const int h = tid & 31, chunk = tid >> 5;
    const int e_lo = chunk * 48;
    float acc = 0.f;
    #pragma unroll
    for (int e = 0; e < 48; ++e)
      acc += rfin[e_lo + e] * W_v[(size_t)(e_lo + e) * HH + h];
    partial[chunk][h] = acc;
  }
  __syncthreads();
  if (tid < HH) {
    float s8 = 0.f;
    #pragma unroll
    for (int c = 0; c < 8; ++c) s8 += partial[c][tid];
    doc_s[tid] = s8 * inv_l + b_v[tid];
  }
  __syncthreads();

  // ---- logits = [doc, q] . W_c + b_c ----
  if (tid < 32) {
    float v = doc_s[tid] * W_c[tid] + q_s[tid] * W_c[HH + tid];
    #pragma unroll
    for (int off = 16; off; off >>= 1) v += __shfl_xor(v, off);
    if (tid == 0) logits[b] = v + b_c[0];
  }
}

extern "C" void kernel_launch(void* const* d_in, const int* in_sizes, int n_in,
                              void* d_out, int out_size, void* d_ws, size_t ws_size,
                              hipStream_t stream) {
  const float* emb       = (const float*)d_in[0];
  const int*   masks     = (const int*)  d_in[1];
  const float* feats     = (const float*)d_in[2];
  const float* W_map     = (const float*)d_in[3];
  const float* b_map     = (const float*)d_in[4];
  const float* trainable = (const float*)d_in[5];
  const float* W_k       = (const float*)d_in[6];
  const float* b_k       = (const float*)d_in[7];
  const float* W_v       = (const float*)d_in[8];
  const float* b_v       = (const float*)d_in[9];
  const float* W_c       = (const float*)d_in[10];
  const float* b_c       = (const float*)d_in[11];

  float* out    = (float*)d_out;
  float* logits = out;            // [B,1] flattened
  float* attn   = out + BB;       // [B, S+1]

  san_fused<<<dim3(BB), dim3(256), 0, stream>>>(
      emb, masks, feats, W_map, b_map, trainable,
      W_k, b_k, W_v, b_v, W_c, b_c, logits, attn);
}